// Round 9
// baseline (151.550 us; speedup 1.0000x reference)
//
#include <hip/hip_runtime.h>

// YOLO loss, fp32. predictions: (batch,7,7,13), target: (batch,7,7,8), out: scalar.
// R8 post-mortem: nt loads broke the 2.7 TB/s plateau -> ~3.5 TB/s (cache
// allocation churn WAS taxing the single-use stream). Known read-mostly
// ceiling on this chip is ~4.9 TB/s (m146) -> not roofline yet. R9: double
// wave-level parallelism. WCELLS 256->128 halves the slab (6656 B/wave,
// 26.6 KB/block) -> 6 blocks/CU = 24 waves/CU; same ~256 KB in flight/CU
// but 2x independent wave streams to smooth nt-read service jitter.
// __launch_bounds__(256,6) caps VGPR at 84 >= ~50 live -> no spill.

static constexpr int PRED_C = 13;   // 5*B + C
static constexpr int TGT_C  = 8;    // 1 + 4 + 3
static constexpr float L_NOOBJ = 0.5f;
static constexpr float L_COORD = 5.0f;
static constexpr float EPSI = 1e-6f;

static constexpr int WCELLS = 128;                  // cells per wave (2 tiles of 64)
static constexpr int SLAB4  = WCELLS * PRED_C / 4;  // 416 float4 = 6656 B/wave

typedef float v4f __attribute__((ext_vector_type(4)));

__device__ __forceinline__ float4 ntload4(const float4* p) {
    v4f v = __builtin_nontemporal_load((const v4f*)p);
    return make_float4(v.x, v.y, v.z, v.w);
}

__device__ __forceinline__ float iou_f(float ax, float ay, float aw, float ah,
                                       float bx, float by, float bw, float bh) {
    float ax1 = ax - aw * 0.5f, ax2 = ax + aw * 0.5f;
    float ay1 = ay - ah * 0.5f, ay2 = ay + ah * 0.5f;
    float bx1 = bx - bw * 0.5f, bx2 = bx + bw * 0.5f;
    float by1 = by - bh * 0.5f, by2 = by + bh * 0.5f;
    float iw = fmaxf(fminf(ax2, bx2) - fmaxf(ax1, bx1), 0.0f);
    float ih = fmaxf(fminf(ay2, by2) - fmaxf(ay1, by1), 0.0f);
    float inter = iw * ih;
    float uni = (ax2 - ax1) * (ay2 - ay1) + (bx2 - bx1) * (by2 - by1) - inter;
    return inter / (uni + EPSI);
}

// ta = target floats 0..3 (obj,x,y,w), tb = floats 4..7 (h, c0,c1,c2)
__device__ __forceinline__ float cell_loss(const float* __restrict__ p,
                                           float4 ta, float4 tb) {
    float m  = (ta.x == 1.0f) ? 1.0f : 0.0f;
    float tx = ta.y, ty = ta.z, tw = ta.w, th = tb.x;

    float b1c = p[0],  b1x = p[1],  b1y = p[2],  b1w = p[3], b1h = p[4];
    float b2c = p[5],  b2x = p[6],  b2y = p[7],  b2w = p[8], b2h = p[9];

    float i1 = iou_f(b1x, b1y, b1w, b1h, tx, ty, tw, th);
    float i2 = iou_f(b2x, b2y, b2w, b2h, tx, ty, tw, th);
    bool pick1 = i1 > i2;
    float iou = pick1 ? i1 : i2;
    float sc  = pick1 ? b1c : b2c;
    float sx  = pick1 ? b1x : b2x;
    float sy  = pick1 ? b1y : b2y;
    float sw  = pick1 ? b1w : b2w;
    float sh  = pick1 ? b1h : b2h;
    float uc  = pick1 ? b2c : b1c;

    float dx = sx - tx, dy = sy - ty;
    // sign(w)*sqrt(|w|): copysign matches jnp.sign semantics for finite inputs.
    float dw = copysignf(sqrtf(fabsf(sw)), sw) - sqrtf(tw);
    float dh = copysignf(sqrtf(fabsf(sh)), sh) - sqrtf(th);
    float l_coord = dx * dx + dy * dy + dw * dw + dh * dh;

    float doj = sc - iou;
    float d0 = p[10] - tb.y, d1 = p[11] - tb.z, d2 = p[12] - tb.w;
    float l_cls = d0 * d0 + d1 * d1 + d2 * d2;
    float l_noobj = m * uc * uc + (1.0f - m) * (b1c * b1c + b2c * b2c);

    return m * (L_COORD * l_coord + doj * doj + l_cls) + L_NOOBJ * l_noobj;
}

__global__ __launch_bounds__(256, 6) void yolo_main(const float* __restrict__ pred,
                                                    const float* __restrict__ tgt,
                                                    float* __restrict__ partial,
                                                    long long ncells) {
    __shared__ float4 sp4[4][SLAB4];   // wave-private 6656 B slab (26.6 KB/block)
    __shared__ float wsum[4];

    const int t    = threadIdx.x;
    const int lane = t & 63;
    const int wave = t >> 6;
    float4* slab4 = sp4[wave];
    const float* slabf = (const float*)slab4;

    const long long gw    = (long long)blockIdx.x * 4 + wave;  // global wave id
    const long long cbase = gw * WCELLS;

    float acc = 0.0f;

    if (cbase + WCELLS <= ncells) {
        // ---- burst: all loads back-to-back (~10.7 KB in flight/wave), nt ----
        // pred: 128 cells * 13 floats = 416 float4 = 6 full rounds + 32 (lane<32)
        const float4* gp4 = (const float4*)pred + gw * SLAB4;
        float4 P0 = ntload4(&gp4[0 * 64 + lane]);
        float4 P1 = ntload4(&gp4[1 * 64 + lane]);
        float4 P2 = ntload4(&gp4[2 * 64 + lane]);
        float4 P3 = ntload4(&gp4[3 * 64 + lane]);
        float4 P4 = ntload4(&gp4[4 * 64 + lane]);
        float4 P5 = ntload4(&gp4[5 * 64 + lane]);
        float4 P6;
        if (lane < 32) P6 = ntload4(&gp4[6 * 64 + lane]);

        const float4* gt4 = (const float4*)tgt;
        float4 T[4];
#pragma unroll
        for (int k = 0; k < 2; ++k) {
            long long cell = cbase + 64 * k + lane;
            T[2 * k]     = ntload4(&gt4[cell * 2]);
            T[2 * k + 1] = ntload4(&gt4[cell * 2 + 1]);
        }

        // ---- park preds in LDS (precise vmcnt waits, oldest-first) ----
        slab4[0 * 64 + lane] = P0;
        slab4[1 * 64 + lane] = P1;
        slab4[2 * 64 + lane] = P2;
        slab4[3 * 64 + lane] = P3;
        slab4[4 * 64 + lane] = P4;
        slab4[5 * 64 + lane] = P5;
        if (lane < 32) slab4[6 * 64 + lane] = P6;

        // ---- compute 2 cells (stride-13 LDS reads: 2 lanes/bank = free) ----
        float pb[PRED_C];
#pragma unroll
        for (int k = 0; k < 2; ++k) {
#pragma unroll
            for (int i = 0; i < PRED_C; ++i)
                pb[i] = slabf[(64 * k + lane) * PRED_C + i];
            acc += cell_loss(pb, T[2 * k], T[2 * k + 1]);
        }
    } else {
        // generic tail (not hit at bench shape: ncells = 3136*512 exact)
        for (int k = 0; k < 2; ++k) {
            long long cell = cbase + 64 * k + lane;
            if (cell < ncells) {
                float pb[PRED_C];
                for (int i = 0; i < PRED_C; ++i) pb[i] = pred[cell * PRED_C + i];
                const float4* gt4 = (const float4*)(tgt + cell * TGT_C);
                acc += cell_loss(pb, gt4[0], gt4[1]);
            }
        }
    }

    // wave64 shuffle reduction -> one partial per block (deterministic)
#pragma unroll
    for (int off = 32; off > 0; off >>= 1)
        acc += __shfl_down(acc, off, 64);
    if (lane == 0) wsum[wave] = acc;
    __syncthreads();
    if (t == 0) partial[blockIdx.x] = (wsum[0] + wsum[1]) + (wsum[2] + wsum[3]);
}

__global__ __launch_bounds__(256) void yolo_reduce(const float* __restrict__ partial,
                                                   float* __restrict__ out,
                                                   int nblocks, float inv_batch) {
    __shared__ float wsum[4];
    int t = threadIdx.x;
    float v = 0.0f;
    for (int i = t; i < nblocks; i += 256) v += partial[i];
#pragma unroll
    for (int off = 32; off > 0; off >>= 1)
        v += __shfl_down(v, off, 64);
    if ((t & 63) == 0) wsum[t >> 6] = v;
    __syncthreads();
    if (t == 0) out[0] = ((wsum[0] + wsum[1]) + (wsum[2] + wsum[3])) * inv_batch;
}

extern "C" void kernel_launch(void* const* d_in, const int* in_sizes, int n_in,
                              void* d_out, int out_size, void* d_ws, size_t ws_size,
                              hipStream_t stream) {
    const float* pred = (const float*)d_in[0];
    const float* tgt  = (const float*)d_in[1];
    float* out = (float*)d_out;
    float* partial = (float*)d_ws;                       // nblocks floats

    long long ncells = (long long)in_sizes[1] / TGT_C;   // batch*S*S = 1,605,632
    long long batch  = ncells / 49;                      // S=7
    float inv_batch  = 1.0f / (float)batch;

    long long cells_per_block = 4LL * WCELLS;            // 512
    int nblocks = (int)((ncells + cells_per_block - 1) / cells_per_block);  // 3136

    yolo_main<<<nblocks, 256, 0, stream>>>(pred, tgt, partial, ncells);
    yolo_reduce<<<1, 256, 0, stream>>>(partial, out, nblocks, inv_batch);
}